// Round 7
// baseline (233.573 us; speedup 1.0000x reference)
//
#include <hip/hip_runtime.h>
#include <math.h>

#define DIN 256
#define DHID 128
#define DOUTC 64
#define EPB 2048   // edges per block in bucket phase 1

typedef __attribute__((ext_vector_type(8))) short short8;
typedef __attribute__((ext_vector_type(4))) float f32x4;

static __device__ __forceinline__ float wave_max(float v){
  #pragma unroll
  for (int o=1;o<64;o<<=1) v = fmaxf(v, __shfl_xor(v,o,64));
  return v;
}
static __device__ __forceinline__ float wave_sum(float v){
  #pragma unroll
  for (int o=1;o<64;o<<=1) v += __shfl_xor(v,o,64);
  return v;
}

static __device__ __forceinline__ unsigned short bf16_rne(float x){
  unsigned int u = __float_as_uint(x);
  return (unsigned short)((u + 0x7FFFu + ((u>>16)&1u)) >> 16);
}
static __device__ __forceinline__ float bf16_to_f32(unsigned short h){
  return __uint_as_float(((unsigned int)h)<<16);
}
static __device__ __forceinline__ float blo(unsigned int u){ return __uint_as_float(u<<16); }
static __device__ __forceinline__ float bhi(unsigned int u){ return __uint_as_float(u & 0xffff0000u); }

// ================= CSR build: atomic-free 2-phase MSD bucket sort =================
__global__ __launch_bounds__(256) void rs_hist(const int* __restrict__ dst,
    int* __restrict__ ghist, int E, int NB){
  __shared__ int h[256];
  const int t = threadIdx.x, blk = blockIdx.x;
  h[t] = 0; __syncthreads();
  const int base = blk*EPB;
  #pragma unroll
  for (int i=0;i<EPB/256;i++){
    int j = base + i*256 + t;
    if (j < E) atomicAdd(&h[dst[j]>>8], 1);
  }
  __syncthreads();
  ghist[t*NB + blk] = h[t];
}

__global__ __launch_bounds__(256) void rs_scan(int* __restrict__ ghist,
    int* __restrict__ btot, int NB){
  __shared__ int b[256];
  __shared__ int carry;
  const int hb = blockIdx.x, t = threadIdx.x;
  if (t==0) carry = 0;
  __syncthreads();
  for (int c0=0; c0<NB; c0+=256){
    int i = c0 + t;
    int v = (i<NB)? ghist[hb*NB+i] : 0;
    b[t] = v; __syncthreads();
    #pragma unroll
    for (int o=1;o<256;o<<=1){
      int x = (t>=o)? b[t-o] : 0;
      __syncthreads();
      b[t] += x;
      __syncthreads();
    }
    if (i<NB) ghist[hb*NB+i] = carry + b[t] - v;   // exclusive
    __syncthreads();
    if (t==255) carry += b[255];
    __syncthreads();
  }
  if (t==255) btot[hb] = carry;
}

__global__ __launch_bounds__(256) void rs_scan2(int* __restrict__ btot,
    int* __restrict__ offsets, int N, int E){
  __shared__ int b[256];
  const int t = threadIdx.x;
  int v = btot[t];
  b[t] = v; __syncthreads();
  #pragma unroll
  for (int o=1;o<256;o<<=1){
    int x = (t>=o)? b[t-o] : 0;
    __syncthreads();
    b[t] += x;
    __syncthreads();
  }
  btot[t] = b[t] - v;                 // exclusive bucket bases
  if (t==255){ btot[256] = E; offsets[N] = E; }
}

__global__ __launch_bounds__(256) void rs_scatter(const int* __restrict__ src,
    const int* __restrict__ dst, const int* __restrict__ ghist,
    const int* __restrict__ btot, uint2* __restrict__ ebuf, int E, int NB){
  __shared__ int cur[256];
  const int t = threadIdx.x, blk = blockIdx.x;
  cur[t] = ghist[t*NB + blk] + btot[t];
  __syncthreads();
  const int base = blk*EPB;
  #pragma unroll
  for (int i=0;i<EPB/256;i++){
    int j = base + i*256 + t;
    if (j < E){
      int d = dst[j];
      int pos = atomicAdd(&cur[d>>8], 1);
      ebuf[pos] = make_uint2((unsigned)src[j], (unsigned)d);
    }
  }
}

__global__ __launch_bounds__(256) void bucket_sort(const uint2* __restrict__ ebuf,
    const int* __restrict__ btot, int* __restrict__ offsets,
    int* __restrict__ srcs, int N){
  __shared__ int h[256];
  __shared__ int b[256];
  const int hb = blockIdx.x, t = threadIdx.x;
  const int b0 = btot[hb], b1 = btot[hb+1];
  h[t] = 0; __syncthreads();
  for (int j=b0+t; j<b1; j+=256) atomicAdd(&h[ebuf[j].y & 255u], 1);
  __syncthreads();
  int v = h[t];
  b[t] = v; __syncthreads();
  #pragma unroll
  for (int o=1;o<256;o<<=1){
    int x = (t>=o)? b[t-o] : 0;
    __syncthreads();
    b[t] += x;
    __syncthreads();
  }
  const int excl = b[t] - v;
  const int node = hb*256 + t;
  if (node < N) offsets[node] = b0 + excl;
  h[t] = excl;
  __syncthreads();
  for (int j=b0+t; j<b1; j+=256){
    uint2 e = ebuf[j];
    int pos = b0 + atomicAdd(&h[e.y & 255u], 1);
    srcs[pos] = (int)e.x;
  }
}

// ---- pack W into MFMA B-fragment order, bf16 hi/lo interleaved (16+16 shorts/lane) ----
template<int K, int NC>
__global__ void pack_kernel(const float* __restrict__ W, unsigned short* __restrict__ Wp){
  constexpr int CT = NC/16, KT = K/32;
  int idx = blockIdx.x*256 + threadIdx.x;
  if (idx >= KT*CT*64) return;
  int l = idx & 63, t = idx >> 6;
  int ct = t % CT, kt = t / CT;
  int col = ct*16 + (l & 15);
  int k0 = kt*32 + (l >> 4)*8;
  unsigned short* dstp = Wp + (size_t)idx*16;
  #pragma unroll
  for (int j=0;j<8;j++){
    float x = W[(size_t)(k0+j)*NC + col];
    unsigned short h = bf16_rne(x);
    dstp[j] = h;
    dstp[8+j] = bf16_rne(x - bf16_to_f32(h));
  }
}

// ---- MFMA GEMM (bf16x3) + fused el/er; 64 rows/block, 4 waves = 2 rowg x 2 colg,
//      explicit A/B register double-buffering (loads for kt+1 issued before MFMAs of kt) ----
template<int K, int NC>
__global__ __launch_bounds__(256) void gemm_mfma(const float* __restrict__ A,
    const unsigned short* __restrict__ Wp,
    const float* __restrict__ al, const float* __restrict__ ar,
    unsigned short* __restrict__ Fb, float* __restrict__ el, float* __restrict__ er, int nrows)
{
  constexpr int CTT = NC/16;      // total col tiles
  constexpr int CTW = CTT/2;      // col tiles per wave (2 col-groups)
  constexpr int KT = K/32;
  __shared__ float pl[64][2], pr[64][2];

  const int lane = threadIdx.x & 63;
  const int wid  = threadIdx.x >> 6;
  const int rg = wid >> 1, cg = wid & 1;
  const int row0 = blockIdx.x*64 + rg*32;
  const int c = lane & 15, g = lane >> 4;

  const int arow0 = row0 + c;
  const int arow1 = row0 + 16 + c;
  const bool ok0 = arow0 < nrows, ok1 = arow1 < nrows;

  f32x4 acc[2][CTW];
  #pragma unroll
  for (int r=0;r<2;r++)
    #pragma unroll
    for (int i=0;i<CTW;i++) acc[r][i] = (f32x4)0.f;

  float4 Ab[2][2][2];    // [parity][r][half]
  short8 Bb[2][CTW][2];  // [parity][ct][hi/lo]
  const float4 z4 = make_float4(0.f,0.f,0.f,0.f);

  // prologue: load kt=0
  {
    const int k0 = g*8;
    Ab[0][0][0] = ok0 ? *(const float4*)&A[(size_t)arow0*K + k0]     : z4;
    Ab[0][0][1] = ok0 ? *(const float4*)&A[(size_t)arow0*K + k0 + 4] : z4;
    Ab[0][1][0] = ok1 ? *(const float4*)&A[(size_t)arow1*K + k0]     : z4;
    Ab[0][1][1] = ok1 ? *(const float4*)&A[(size_t)arow1*K + k0 + 4] : z4;
    #pragma unroll
    for (int ct=0; ct<CTW; ++ct){
      const size_t base = (((size_t)(cg*CTW + ct))*64 + lane)*16;
      Bb[0][ct][0] = *(const short8*)&Wp[base];
      Bb[0][ct][1] = *(const short8*)&Wp[base+8];
    }
  }

  #pragma unroll
  for (int kt=0; kt<KT; ++kt){
    const int cur = kt & 1, nxt = cur ^ 1;
    if (kt+1 < KT){
      const int k0 = (kt+1)*32 + g*8;
      Ab[nxt][0][0] = ok0 ? *(const float4*)&A[(size_t)arow0*K + k0]     : z4;
      Ab[nxt][0][1] = ok0 ? *(const float4*)&A[(size_t)arow0*K + k0 + 4] : z4;
      Ab[nxt][1][0] = ok1 ? *(const float4*)&A[(size_t)arow1*K + k0]     : z4;
      Ab[nxt][1][1] = ok1 ? *(const float4*)&A[(size_t)arow1*K + k0 + 4] : z4;
      #pragma unroll
      for (int ct=0; ct<CTW; ++ct){
        const size_t base = (((size_t)((kt+1)*CTT + cg*CTW + ct))*64 + lane)*16;
        Bb[nxt][ct][0] = *(const short8*)&Wp[base];
        Bb[nxt][ct][1] = *(const short8*)&Wp[base+8];
      }
    }
    // convert A (current parity) to bf16 hi/lo
    short8 ahi[2], alo[2];
    #pragma unroll
    for (int r=0;r<2;r++){
      float xs[8];
      xs[0]=Ab[cur][r][0].x; xs[1]=Ab[cur][r][0].y; xs[2]=Ab[cur][r][0].z; xs[3]=Ab[cur][r][0].w;
      xs[4]=Ab[cur][r][1].x; xs[5]=Ab[cur][r][1].y; xs[6]=Ab[cur][r][1].z; xs[7]=Ab[cur][r][1].w;
      #pragma unroll
      for (int j=0;j<8;j++){
        unsigned short hh = bf16_rne(xs[j]);
        ahi[r][j] = (short)hh;
        alo[r][j] = (short)bf16_rne(xs[j] - bf16_to_f32(hh));
      }
    }
    #pragma unroll
    for (int ct=0; ct<CTW; ++ct){
      #pragma unroll
      for (int r=0;r<2;r++){
        acc[r][ct] = __builtin_amdgcn_mfma_f32_16x16x32_bf16(ahi[r], Bb[cur][ct][0], acc[r][ct], 0,0,0);
        acc[r][ct] = __builtin_amdgcn_mfma_f32_16x16x32_bf16(alo[r], Bb[cur][ct][0], acc[r][ct], 0,0,0);
        acc[r][ct] = __builtin_amdgcn_mfma_f32_16x16x32_bf16(ahi[r], Bb[cur][ct][1], acc[r][ct], 0,0,0);
      }
    }
  }

  // epilogue: C/D layout row=(lane>>4)*4+j (+r*16), col=lane&15 within tile.
  float alv[CTW], arv[CTW];
  #pragma unroll
  for (int ct=0;ct<CTW;ct++){
    alv[ct] = al[cg*CTW*16 + ct*16 + c];
    arv[ct] = ar[cg*CTW*16 + ct*16 + c];
  }
  #pragma unroll
  for (int r=0;r<2;r++){
    #pragma unroll
    for (int j=0;j<4;j++){
      const int row = row0 + r*16 + g*4 + j;
      const bool ok = row < nrows;
      float sl=0.f, sr=0.f;
      #pragma unroll
      for (int ct=0;ct<CTW;ct++){
        float f = acc[r][ct][j];
        sl = fmaf(f, alv[ct], sl);
        sr = fmaf(f, arv[ct], sr);
        if (ok) Fb[(size_t)row*NC + cg*CTW*16 + ct*16 + c] = bf16_rne(f);
      }
      #pragma unroll
      for (int o=1;o<16;o<<=1){ sl += __shfl_xor(sl,o,64); sr += __shfl_xor(sr,o,64); }
      if (c==0){
        pl[rg*32 + r*16 + g*4 + j][cg] = sl;
        pr[rg*32 + r*16 + g*4 + j][cg] = sr;
      }
    }
  }
  __syncthreads();
  if (threadIdx.x < 64){
    const int row = blockIdx.x*64 + threadIdx.x;
    if (row < nrows){
      el[row] = pl[threadIdx.x][0] + pl[threadIdx.x][1];
      er[row] = pr[threadIdx.x][0] + pr[threadIdx.x][1];
    }
  }
}

// ---------------- per-node online edge softmax + aggregate ----------------
template<int D, bool RELU, bool LOGSM>
__global__ __launch_bounds__(256) void agg3_kernel(const unsigned short* __restrict__ Fb,
    const float* __restrict__ el, const float* __restrict__ er,
    const int* __restrict__ offsets, const int* __restrict__ srcs,
    float* __restrict__ out, int N)
{
  constexpr int CPL = D/16;
  __shared__ float2 ws[4][64];
  const int wv = threadIdx.x >> 6;
  const int lane = threadIdx.x & 63;
  const int c16 = lane & 15, g = lane >> 4;
  const int v = blockIdx.x*4 + wv;
  if (v >= N) return;
  const int o0 = offsets[v], o1 = offsets[v+1];
  const float erv = er[v];

  float m = -INFINITY, z = 0.f;
  float acc[CPL];
  #pragma unroll
  for (int i=0;i<CPL;i++) acc[i]=0.f;

  for (int s0 = o0; s0 < o1; s0 += 64){
    const int j = s0 + lane;
    int sidx = 0; float e = -INFINITY;
    if (j < o1){
      sidx = srcs[j];
      float tv = el[sidx] + erv;
      e = (tv > 0.f) ? tv : 0.2f*tv;
    }
    const float nm = fmaxf(m, wave_max(e));
    const float scale = __expf(m - nm);
    const float wgt = __expf(e - nm);
    z = z*scale + wave_sum(wgt);
    #pragma unroll
    for (int i=0;i<CPL;i++) acc[i] *= scale;
    m = nm;
    ws[wv][lane] = make_float2(wgt, __int_as_float(sidx));
    __builtin_amdgcn_wave_barrier();

    const int cnt = min(64, o1 - s0);
    int t = g;
    if (D == 128){
      for (; t+4 < cnt; t += 8){
        float2 p0 = ws[wv][t], p1 = ws[wv][t+4];
        uint4 u0 = *((const uint4*)(Fb + (size_t)__float_as_int(p0.y)*128) + c16);
        uint4 u1 = *((const uint4*)(Fb + (size_t)__float_as_int(p1.y)*128) + c16);
        acc[0]=fmaf(p0.x, blo(u0.x), acc[0]); acc[1]=fmaf(p0.x, bhi(u0.x), acc[1]);
        acc[2]=fmaf(p0.x, blo(u0.y), acc[2]); acc[3]=fmaf(p0.x, bhi(u0.y), acc[3]);
        acc[4]=fmaf(p0.x, blo(u0.z), acc[4]); acc[5]=fmaf(p0.x, bhi(u0.z), acc[5]);
        acc[6]=fmaf(p0.x, blo(u0.w), acc[6]); acc[7]=fmaf(p0.x, bhi(u0.w), acc[7]);
        acc[0]=fmaf(p1.x, blo(u1.x), acc[0]); acc[1]=fmaf(p1.x, bhi(u1.x), acc[1]);
        acc[2]=fmaf(p1.x, blo(u1.y), acc[2]); acc[3]=fmaf(p1.x, bhi(u1.y), acc[3]);
        acc[4]=fmaf(p1.x, blo(u1.z), acc[4]); acc[5]=fmaf(p1.x, bhi(u1.z), acc[5]);
        acc[6]=fmaf(p1.x, blo(u1.w), acc[6]); acc[7]=fmaf(p1.x, bhi(u1.w), acc[7]);
      }
      if (t < cnt){
        float2 p0 = ws[wv][t];
        uint4 u0 = *((const uint4*)(Fb + (size_t)__float_as_int(p0.y)*128) + c16);
        acc[0]=fmaf(p0.x, blo(u0.x), acc[0]); acc[1]=fmaf(p0.x, bhi(u0.x), acc[1]);
        acc[2]=fmaf(p0.x, blo(u0.y), acc[2]); acc[3]=fmaf(p0.x, bhi(u0.y), acc[3]);
        acc[4]=fmaf(p0.x, blo(u0.z), acc[4]); acc[5]=fmaf(p0.x, bhi(u0.z), acc[5]);
        acc[6]=fmaf(p0.x, blo(u0.w), acc[6]); acc[7]=fmaf(p0.x, bhi(u0.w), acc[7]);
      }
    } else {
      for (; t+4 < cnt; t += 8){
        float2 p0 = ws[wv][t], p1 = ws[wv][t+4];
        uint2 u0 = *((const uint2*)(Fb + (size_t)__float_as_int(p0.y)*64) + c16);
        uint2 u1 = *((const uint2*)(Fb + (size_t)__float_as_int(p1.y)*64) + c16);
        acc[0]=fmaf(p0.x, blo(u0.x), acc[0]); acc[1]=fmaf(p0.x, bhi(u0.x), acc[1]);
        acc[2]=fmaf(p0.x, blo(u0.y), acc[2]); acc[3]=fmaf(p0.x, bhi(u0.y), acc[3]);
        acc[0]=fmaf(p1.x, blo(u1.x), acc[0]); acc[1]=fmaf(p1.x, bhi(u1.x), acc[1]);
        acc[2]=fmaf(p1.x, blo(u1.y), acc[2]); acc[3]=fmaf(p1.x, bhi(u1.y), acc[3]);
      }
      if (t < cnt){
        float2 p0 = ws[wv][t];
        uint2 u0 = *((const uint2*)(Fb + (size_t)__float_as_int(p0.y)*64) + c16);
        acc[0]=fmaf(p0.x, blo(u0.x), acc[0]); acc[1]=fmaf(p0.x, bhi(u0.x), acc[1]);
        acc[2]=fmaf(p0.x, blo(u0.y), acc[2]); acc[3]=fmaf(p0.x, bhi(u0.y), acc[3]);
      }
    }
    __builtin_amdgcn_wave_barrier();
  }

  #pragma unroll
  for (int i=0;i<CPL;i++){
    acc[i] += __shfl_xor(acc[i],16,64);
    acc[i] += __shfl_xor(acc[i],32,64);
  }
  const float zi = 1.f / fmaxf(z, 1e-9f);

  if (LOGSM){
    float y[CPL];
    #pragma unroll
    for (int i=0;i<CPL;i++) y[i] = acc[i]*zi;
    float M = y[0];
    #pragma unroll
    for (int i=1;i<CPL;i++) M = fmaxf(M, y[i]);
    #pragma unroll
    for (int o=1;o<16;o<<=1) M = fmaxf(M, __shfl_xor(M,o,64));
    float ssum = 0.f;
    #pragma unroll
    for (int i=0;i<CPL;i++) ssum += __expf(y[i]-M);
    #pragma unroll
    for (int o=1;o<16;o<<=1) ssum += __shfl_xor(ssum,o,64);
    const float lw = M + logf(ssum);
    if (g==0){
      float4 r = make_float4(y[0]-lw, y[1]-lw, y[2]-lw, y[3]-lw);
      *(float4*)&out[(size_t)v*64 + c16*4] = r;
    }
  } else {
    if (g==0){
      float r[CPL];
      #pragma unroll
      for (int i=0;i<CPL;i++){ r[i]=acc[i]*zi; if (RELU) r[i]=fmaxf(r[i],0.f); }
      *(float4*)&out[(size_t)v*128 + c16*8]     = make_float4(r[0],r[1],r[2],r[3]);
      *(float4*)&out[(size_t)v*128 + c16*8 + 4] = make_float4(r[4],r[5],r[6],r[7]);
    }
  }
}

// ---------------- launch ----------------
extern "C" void kernel_launch(void* const* d_in, const int* in_sizes, int n_in,
                              void* d_out, int out_size, void* d_ws, size_t ws_size,
                              hipStream_t stream) {
  const float* h   = (const float*)d_in[0];
  const int*   src = (const int*)d_in[1];
  const int*   dst = (const int*)d_in[2];
  const float* W1  = (const float*)d_in[3];
  const float* al1 = (const float*)d_in[4];
  const float* ar1 = (const float*)d_in[5];
  const float* W2  = (const float*)d_in[6];
  const float* al2 = (const float*)d_in[7];
  const float* ar2 = (const float*)d_in[8];
  const float* W3  = (const float*)d_in[9];
  const float* al3 = (const float*)d_in[10];
  const float* ar3 = (const float*)d_in[11];

  const int N = in_sizes[0] / DIN;
  const int E = in_sizes[1];
  const int NB = (E + EPB - 1) / EPB;
  const int NHB = (N + 255) / 256;

  auto alignup = [](size_t x){ return (x + 255) & ~(size_t)255; };
  char* p = (char*)d_ws;
  int* offsets = (int*)p; p += alignup(((size_t)N+1)*4);
  int* srcs    = (int*)p; p += alignup((size_t)E*4);
  int* ghist   = (int*)p; p += alignup((size_t)256*NB*4);
  int* btot    = (int*)p; p += alignup(257*4);
  uint2* ebuf  = (uint2*)p; p += alignup((size_t)E*8);
  unsigned short* Fb = (unsigned short*)p; p += alignup((size_t)N*DHID*2);
  float* X     = (float*)p; p += alignup((size_t)N*DHID*4);
  float* el    = (float*)p; p += alignup((size_t)N*4);
  float* er    = (float*)p; p += alignup((size_t)N*4);
  unsigned short* Wp1 = (unsigned short*)p; p += alignup((size_t)2*DIN*DHID*2);
  unsigned short* Wp2 = (unsigned short*)p; p += alignup((size_t)2*DHID*DHID*2);
  unsigned short* Wp3 = (unsigned short*)p; p += alignup((size_t)2*DHID*DOUTC*2);

  const int nbW4 = (N+3)/4;
  const int nbG  = (N+63)/64;   // 64 rows/block, 4 waves (2 rowg x 2 colg)

  pack_kernel<DIN ,DHID ><<<(DIN/32)*(DHID/16)*64/256,  256,0,stream>>>(W1, Wp1);
  pack_kernel<DHID,DHID ><<<(DHID/32)*(DHID/16)*64/256, 256,0,stream>>>(W2, Wp2);
  pack_kernel<DHID,DOUTC><<<(DHID/32)*(DOUTC/16)*64/256,256,0,stream>>>(W3, Wp3);

  // CSR build (atomic-free)
  rs_hist   <<<NB, 256,0,stream>>>(dst, ghist, E, NB);
  rs_scan   <<<256,256,0,stream>>>(ghist, btot, NB);
  rs_scan2  <<<1,  256,0,stream>>>(btot, offsets, N, E);
  rs_scatter<<<NB, 256,0,stream>>>(src, dst, ghist, btot, ebuf, E, NB);
  bucket_sort<<<NHB,256,0,stream>>>(ebuf, btot, offsets, srcs, N);

  // Layer 1: [N,256]@[256,128]
  gemm_mfma<DIN,DHID><<<nbG,256,0,stream>>>(h, Wp1, al1, ar1, Fb, el, er, N);
  agg3_kernel<128,true,false><<<nbW4,256,0,stream>>>(Fb, el, er, offsets, srcs, X, N);

  // Layer 2: [N,128]@[128,128]
  gemm_mfma<DHID,DHID><<<nbG,256,0,stream>>>(X, Wp2, al2, ar2, Fb, el, er, N);
  agg3_kernel<128,true,false><<<nbW4,256,0,stream>>>(Fb, el, er, offsets, srcs, X, N);

  // Layer 3: [N,128]@[128,64] + log_softmax
  gemm_mfma<DHID,DOUTC><<<nbG,256,0,stream>>>(X, Wp3, al3, ar3, Fb, el, er, N);
  agg3_kernel<64,false,true><<<nbW4,256,0,stream>>>(Fb, el, er, offsets, srcs, (float*)d_out, N);
}

// Round 8
// 180.251 us; speedup vs baseline: 1.2958x; 1.2958x over previous
//
#include <hip/hip_runtime.h>
#include <math.h>

#define DIN 256
#define DHID 128
#define DOUTC 64
#define EPB 2048   // edges per block in bucket phase 1

typedef __attribute__((ext_vector_type(8))) short short8;
typedef __attribute__((ext_vector_type(4))) float f32x4;

static __device__ __forceinline__ float wave_max(float v){
  #pragma unroll
  for (int o=1;o<64;o<<=1) v = fmaxf(v, __shfl_xor(v,o,64));
  return v;
}
static __device__ __forceinline__ float wave_sum(float v){
  #pragma unroll
  for (int o=1;o<64;o<<=1) v += __shfl_xor(v,o,64);
  return v;
}

static __device__ __forceinline__ unsigned short bf16_rne(float x){
  unsigned int u = __float_as_uint(x);
  return (unsigned short)((u + 0x7FFFu + ((u>>16)&1u)) >> 16);
}
static __device__ __forceinline__ float bf16_to_f32(unsigned short h){
  return __uint_as_float(((unsigned int)h)<<16);
}
static __device__ __forceinline__ float blo(unsigned int u){ return __uint_as_float(u<<16); }
static __device__ __forceinline__ float bhi(unsigned int u){ return __uint_as_float(u & 0xffff0000u); }

// ================= CSR build: atomic-free 2-phase MSD bucket sort =================
__global__ __launch_bounds__(256) void rs_hist(const int* __restrict__ dst,
    int* __restrict__ ghist, int E, int NB){
  __shared__ int h[256];
  const int t = threadIdx.x, blk = blockIdx.x;
  h[t] = 0; __syncthreads();
  const int base = blk*EPB;
  #pragma unroll
  for (int i=0;i<EPB/256;i++){
    int j = base + i*256 + t;
    if (j < E) atomicAdd(&h[dst[j]>>8], 1);
  }
  __syncthreads();
  ghist[t*NB + blk] = h[t];
}

__global__ __launch_bounds__(256) void rs_scan(int* __restrict__ ghist,
    int* __restrict__ btot, int NB){
  __shared__ int b[256];
  __shared__ int carry;
  const int hb = blockIdx.x, t = threadIdx.x;
  if (t==0) carry = 0;
  __syncthreads();
  for (int c0=0; c0<NB; c0+=256){
    int i = c0 + t;
    int v = (i<NB)? ghist[hb*NB+i] : 0;
    b[t] = v; __syncthreads();
    #pragma unroll
    for (int o=1;o<256;o<<=1){
      int x = (t>=o)? b[t-o] : 0;
      __syncthreads();
      b[t] += x;
      __syncthreads();
    }
    if (i<NB) ghist[hb*NB+i] = carry + b[t] - v;   // exclusive
    __syncthreads();
    if (t==255) carry += b[255];
    __syncthreads();
  }
  if (t==255) btot[hb] = carry;
}

__global__ __launch_bounds__(256) void rs_scan2(int* __restrict__ btot,
    int* __restrict__ offsets, int N, int E){
  __shared__ int b[256];
  const int t = threadIdx.x;
  int v = btot[t];
  b[t] = v; __syncthreads();
  #pragma unroll
  for (int o=1;o<256;o<<=1){
    int x = (t>=o)? b[t-o] : 0;
    __syncthreads();
    b[t] += x;
    __syncthreads();
  }
  btot[t] = b[t] - v;                 // exclusive bucket bases
  if (t==255){ btot[256] = E; offsets[N] = E; }
}

__global__ __launch_bounds__(256) void rs_scatter(const int* __restrict__ src,
    const int* __restrict__ dst, const int* __restrict__ ghist,
    const int* __restrict__ btot, uint2* __restrict__ ebuf, int E, int NB){
  __shared__ int cur[256];
  const int t = threadIdx.x, blk = blockIdx.x;
  cur[t] = ghist[t*NB + blk] + btot[t];
  __syncthreads();
  const int base = blk*EPB;
  #pragma unroll
  for (int i=0;i<EPB/256;i++){
    int j = base + i*256 + t;
    if (j < E){
      int d = dst[j];
      int pos = atomicAdd(&cur[d>>8], 1);
      ebuf[pos] = make_uint2((unsigned)src[j], (unsigned)d);
    }
  }
}

__global__ __launch_bounds__(256) void bucket_sort(const uint2* __restrict__ ebuf,
    const int* __restrict__ btot, int* __restrict__ offsets,
    int* __restrict__ srcs, int N){
  __shared__ int h[256];
  __shared__ int b[256];
  const int hb = blockIdx.x, t = threadIdx.x;
  const int b0 = btot[hb], b1 = btot[hb+1];
  h[t] = 0; __syncthreads();
  for (int j=b0+t; j<b1; j+=256) atomicAdd(&h[ebuf[j].y & 255u], 1);
  __syncthreads();
  int v = h[t];
  b[t] = v; __syncthreads();
  #pragma unroll
  for (int o=1;o<256;o<<=1){
    int x = (t>=o)? b[t-o] : 0;
    __syncthreads();
    b[t] += x;
    __syncthreads();
  }
  const int excl = b[t] - v;
  const int node = hb*256 + t;
  if (node < N) offsets[node] = b0 + excl;
  h[t] = excl;
  __syncthreads();
  for (int j=b0+t; j<b1; j+=256){
    uint2 e = ebuf[j];
    int pos = b0 + atomicAdd(&h[e.y & 255u], 1);
    srcs[pos] = (int)e.x;
  }
}

// ---- pack W into MFMA B-fragment order, single bf16 (8 shorts = 16 B per lane/frag) ----
// Fragment fi = kt*CT+ct, lane l: B[k = kt*32 + 8*(l>>4)+j][col = ct*16 + (l&15)], j=0..7
template<int K, int NC>
__global__ void pack_kernel(const float* __restrict__ W, unsigned short* __restrict__ Wp){
  constexpr int CT = NC/16, KT = K/32;
  int idx = blockIdx.x*256 + threadIdx.x;
  if (idx >= KT*CT*64) return;
  int l = idx & 63, t = idx >> 6;
  int ct = t % CT, kt = t / CT;
  int col = ct*16 + (l & 15);
  int k0 = kt*32 + (l >> 4)*8;
  unsigned short* dstp = Wp + (size_t)idx*8;
  #pragma unroll
  for (int j=0;j<8;j++)
    dstp[j] = bf16_rne(W[(size_t)(k0+j)*NC + col]);
}

// ---- MFMA GEMM (bf16x2: A hi/lo fp32-class, B single bf16 staged in LDS) + fused el/er ----
// 256 thr / 4 waves / 64 rows per block; each wave: 16 rows x all NC cols.
// B staged chunk-wise (<=32 KB) in LDS; per kt: 2 A float4 loads, CT ds_read_b128, 2*CT MFMAs.
template<int K, int NC>
__global__ __launch_bounds__(256) void gemm_v3(const float* __restrict__ A,
    const unsigned short* __restrict__ Wp,
    const float* __restrict__ al, const float* __restrict__ ar,
    unsigned short* __restrict__ Fb, float* __restrict__ el, float* __restrict__ er, int nrows)
{
  constexpr int CT = NC/16, KT = K/32;
  constexpr int CHUNK_KT = (32/CT) < KT ? (32/CT) : KT;   // kt-steps per LDS chunk (<=32 KB)
  constexpr int NCHUNK = KT / CHUNK_KT;
  constexpr int CHUNK_SHORTS = CHUNK_KT*CT*64*8;
  __shared__ unsigned short bsm[CHUNK_SHORTS];

  const int tid = threadIdx.x;
  const int lane = tid & 63;
  const int wid  = tid >> 6;
  const int row0 = blockIdx.x*64 + wid*16;
  const int c = lane & 15, g = lane >> 4;
  const int arow = row0 + c;
  const bool aok = arow < nrows;

  f32x4 acc[CT];
  #pragma unroll
  for (int i=0;i<CT;i++) acc[i] = (f32x4)0.f;

  for (int ch=0; ch<NCHUNK; ++ch){
    if (ch) __syncthreads();
    // cooperative stage of this W chunk into LDS (linear copy, 16 B per thread per iter)
    {
      const uint4* gsrc = (const uint4*)Wp + (size_t)ch*(CHUNK_SHORTS/8);
      uint4* ldst = (uint4*)bsm;
      #pragma unroll
      for (int i=0; i<CHUNK_SHORTS/8/256; ++i)
        ldst[i*256 + tid] = gsrc[i*256 + tid];
    }
    __syncthreads();

    #pragma unroll
    for (int ktl=0; ktl<CHUNK_KT; ++ktl){
      const int k0 = (ch*CHUNK_KT + ktl)*32 + g*8;
      float xs[8];
      if (aok){
        float4 v0 = *(const float4*)&A[(size_t)arow*K + k0];
        float4 v1 = *(const float4*)&A[(size_t)arow*K + k0 + 4];
        xs[0]=v0.x; xs[1]=v0.y; xs[2]=v0.z; xs[3]=v0.w;
        xs[4]=v1.x; xs[5]=v1.y; xs[6]=v1.z; xs[7]=v1.w;
      } else {
        #pragma unroll
        for (int j=0;j<8;j++) xs[j]=0.f;
      }
      short8 ahi, alo;
      #pragma unroll
      for (int j=0;j<8;j++){
        unsigned short hh = bf16_rne(xs[j]);
        ahi[j] = (short)hh;
        alo[j] = (short)bf16_rne(xs[j] - bf16_to_f32(hh));
      }
      #pragma unroll
      for (int ct=0; ct<CT; ++ct){
        short8 b = *(const short8*)&bsm[(ktl*CT+ct)*512 + lane*8];
        acc[ct] = __builtin_amdgcn_mfma_f32_16x16x32_bf16(ahi, b, acc[ct], 0,0,0);
        acc[ct] = __builtin_amdgcn_mfma_f32_16x16x32_bf16(alo, b, acc[ct], 0,0,0);
      }
    }
  }

  // epilogue: C/D layout row=(lane>>4)*4+j, col=lane&15. Store bf16 F + fused el/er.
  float alv[CT], arv[CT];
  #pragma unroll
  for (int ct=0;ct<CT;ct++){ alv[ct]=al[ct*16+c]; arv[ct]=ar[ct*16+c]; }
  #pragma unroll
  for (int j=0;j<4;j++){
    const int row = row0 + g*4 + j;
    const bool ok = row < nrows;
    float sl=0.f, sr=0.f;
    #pragma unroll
    for (int ct=0;ct<CT;ct++){
      float f = acc[ct][j];
      sl = fmaf(f, alv[ct], sl);
      sr = fmaf(f, arv[ct], sr);
      if (ok) Fb[(size_t)row*NC + ct*16 + c] = bf16_rne(f);
    }
    #pragma unroll
    for (int o=1;o<16;o<<=1){ sl += __shfl_xor(sl,o,64); sr += __shfl_xor(sr,o,64); }
    if (ok && c==0){ el[row]=sl; er[row]=sr; }
  }
}

// ---------------- per-node online edge softmax + aggregate ----------------
template<int D, bool RELU, bool LOGSM>
__global__ __launch_bounds__(256) void agg3_kernel(const unsigned short* __restrict__ Fb,
    const float* __restrict__ el, const float* __restrict__ er,
    const int* __restrict__ offsets, const int* __restrict__ srcs,
    float* __restrict__ out, int N)
{
  constexpr int CPL = D/16;
  __shared__ float2 ws[4][64];
  const int wv = threadIdx.x >> 6;
  const int lane = threadIdx.x & 63;
  const int c16 = lane & 15, g = lane >> 4;
  const int v = blockIdx.x*4 + wv;
  if (v >= N) return;
  const int o0 = offsets[v], o1 = offsets[v+1];
  const float erv = er[v];

  float m = -INFINITY, z = 0.f;
  float acc[CPL];
  #pragma unroll
  for (int i=0;i<CPL;i++) acc[i]=0.f;

  for (int s0 = o0; s0 < o1; s0 += 64){
    const int j = s0 + lane;
    int sidx = 0; float e = -INFINITY;
    if (j < o1){
      sidx = srcs[j];
      float tv = el[sidx] + erv;
      e = (tv > 0.f) ? tv : 0.2f*tv;
    }
    const float nm = fmaxf(m, wave_max(e));
    const float scale = __expf(m - nm);
    const float wgt = __expf(e - nm);
    z = z*scale + wave_sum(wgt);
    #pragma unroll
    for (int i=0;i<CPL;i++) acc[i] *= scale;
    m = nm;
    ws[wv][lane] = make_float2(wgt, __int_as_float(sidx));
    __builtin_amdgcn_wave_barrier();

    const int cnt = min(64, o1 - s0);
    int t = g;
    if (D == 128){
      for (; t+4 < cnt; t += 8){
        float2 p0 = ws[wv][t], p1 = ws[wv][t+4];
        uint4 u0 = *((const uint4*)(Fb + (size_t)__float_as_int(p0.y)*128) + c16);
        uint4 u1 = *((const uint4*)(Fb + (size_t)__float_as_int(p1.y)*128) + c16);
        acc[0]=fmaf(p0.x, blo(u0.x), acc[0]); acc[1]=fmaf(p0.x, bhi(u0.x), acc[1]);
        acc[2]=fmaf(p0.x, blo(u0.y), acc[2]); acc[3]=fmaf(p0.x, bhi(u0.y), acc[3]);
        acc[4]=fmaf(p0.x, blo(u0.z), acc[4]); acc[5]=fmaf(p0.x, bhi(u0.z), acc[5]);
        acc[6]=fmaf(p0.x, blo(u0.w), acc[6]); acc[7]=fmaf(p0.x, bhi(u0.w), acc[7]);
        acc[0]=fmaf(p1.x, blo(u1.x), acc[0]); acc[1]=fmaf(p1.x, bhi(u1.x), acc[1]);
        acc[2]=fmaf(p1.x, blo(u1.y), acc[2]); acc[3]=fmaf(p1.x, bhi(u1.y), acc[3]);
        acc[4]=fmaf(p1.x, blo(u1.z), acc[4]); acc[5]=fmaf(p1.x, bhi(u1.z), acc[5]);
        acc[6]=fmaf(p1.x, blo(u1.w), acc[6]); acc[7]=fmaf(p1.x, bhi(u1.w), acc[7]);
      }
      if (t < cnt){
        float2 p0 = ws[wv][t];
        uint4 u0 = *((const uint4*)(Fb + (size_t)__float_as_int(p0.y)*128) + c16);
        acc[0]=fmaf(p0.x, blo(u0.x), acc[0]); acc[1]=fmaf(p0.x, bhi(u0.x), acc[1]);
        acc[2]=fmaf(p0.x, blo(u0.y), acc[2]); acc[3]=fmaf(p0.x, bhi(u0.y), acc[3]);
        acc[4]=fmaf(p0.x, blo(u0.z), acc[4]); acc[5]=fmaf(p0.x, bhi(u0.z), acc[5]);
        acc[6]=fmaf(p0.x, blo(u0.w), acc[6]); acc[7]=fmaf(p0.x, bhi(u0.w), acc[7]);
      }
    } else {
      for (; t+4 < cnt; t += 8){
        float2 p0 = ws[wv][t], p1 = ws[wv][t+4];
        uint2 u0 = *((const uint2*)(Fb + (size_t)__float_as_int(p0.y)*64) + c16);
        uint2 u1 = *((const uint2*)(Fb + (size_t)__float_as_int(p1.y)*64) + c16);
        acc[0]=fmaf(p0.x, blo(u0.x), acc[0]); acc[1]=fmaf(p0.x, bhi(u0.x), acc[1]);
        acc[2]=fmaf(p0.x, blo(u0.y), acc[2]); acc[3]=fmaf(p0.x, bhi(u0.y), acc[3]);
        acc[0]=fmaf(p1.x, blo(u1.x), acc[0]); acc[1]=fmaf(p1.x, bhi(u1.x), acc[1]);
        acc[2]=fmaf(p1.x, blo(u1.y), acc[2]); acc[3]=fmaf(p1.x, bhi(u1.y), acc[3]);
      }
      if (t < cnt){
        float2 p0 = ws[wv][t];
        uint2 u0 = *((const uint2*)(Fb + (size_t)__float_as_int(p0.y)*64) + c16);
        acc[0]=fmaf(p0.x, blo(u0.x), acc[0]); acc[1]=fmaf(p0.x, bhi(u0.x), acc[1]);
        acc[2]=fmaf(p0.x, blo(u0.y), acc[2]); acc[3]=fmaf(p0.x, bhi(u0.y), acc[3]);
      }
    }
    __builtin_amdgcn_wave_barrier();
  }

  #pragma unroll
  for (int i=0;i<CPL;i++){
    acc[i] += __shfl_xor(acc[i],16,64);
    acc[i] += __shfl_xor(acc[i],32,64);
  }
  const float zi = 1.f / fmaxf(z, 1e-9f);

  if (LOGSM){
    float y[CPL];
    #pragma unroll
    for (int i=0;i<CPL;i++) y[i] = acc[i]*zi;
    float M = y[0];
    #pragma unroll
    for (int i=1;i<CPL;i++) M = fmaxf(M, y[i]);
    #pragma unroll
    for (int o=1;o<16;o<<=1) M = fmaxf(M, __shfl_xor(M,o,64));
    float ssum = 0.f;
    #pragma unroll
    for (int i=0;i<CPL;i++) ssum += __expf(y[i]-M);
    #pragma unroll
    for (int o=1;o<16;o<<=1) ssum += __shfl_xor(ssum,o,64);
    const float lw = M + logf(ssum);
    if (g==0){
      float4 r = make_float4(y[0]-lw, y[1]-lw, y[2]-lw, y[3]-lw);
      *(float4*)&out[(size_t)v*64 + c16*4] = r;
    }
  } else {
    if (g==0){
      float r[CPL];
      #pragma unroll
      for (int i=0;i<CPL;i++){ r[i]=acc[i]*zi; if (RELU) r[i]=fmaxf(r[i],0.f); }
      *(float4*)&out[(size_t)v*128 + c16*8]     = make_float4(r[0],r[1],r[2],r[3]);
      *(float4*)&out[(size_t)v*128 + c16*8 + 4] = make_float4(r[4],r[5],r[6],r[7]);
    }
  }
}

// ---------------- launch ----------------
extern "C" void kernel_launch(void* const* d_in, const int* in_sizes, int n_in,
                              void* d_out, int out_size, void* d_ws, size_t ws_size,
                              hipStream_t stream) {
  const float* h   = (const float*)d_in[0];
  const int*   src = (const int*)d_in[1];
  const int*   dst = (const int*)d_in[2];
  const float* W1  = (const float*)d_in[3];
  const float* al1 = (const float*)d_in[4];
  const float* ar1 = (const float*)d_in[5];
  const float* W2  = (const float*)d_in[6];
  const float* al2 = (const float*)d_in[7];
  const float* ar2 = (const float*)d_in[8];
  const float* W3  = (const float*)d_in[9];
  const float* al3 = (const float*)d_in[10];
  const float* ar3 = (const float*)d_in[11];

  const int N = in_sizes[0] / DIN;
  const int E = in_sizes[1];
  const int NB = (E + EPB - 1) / EPB;
  const int NHB = (N + 255) / 256;

  auto alignup = [](size_t x){ return (x + 255) & ~(size_t)255; };
  char* p = (char*)d_ws;
  int* offsets = (int*)p; p += alignup(((size_t)N+1)*4);
  int* srcs    = (int*)p; p += alignup((size_t)E*4);
  int* ghist   = (int*)p; p += alignup((size_t)256*NB*4);
  int* btot    = (int*)p; p += alignup(257*4);
  uint2* ebuf  = (uint2*)p; p += alignup((size_t)E*8);
  unsigned short* Fb = (unsigned short*)p; p += alignup((size_t)N*DHID*2);
  float* X     = (float*)p; p += alignup((size_t)N*DHID*4);
  float* el    = (float*)p; p += alignup((size_t)N*4);
  float* er    = (float*)p; p += alignup((size_t)N*4);
  unsigned short* Wp1 = (unsigned short*)p; p += alignup((size_t)(DIN/32)*(DHID/16)*64*8*2);
  unsigned short* Wp2 = (unsigned short*)p; p += alignup((size_t)(DHID/32)*(DHID/16)*64*8*2);
  unsigned short* Wp3 = (unsigned short*)p; p += alignup((size_t)(DHID/32)*(DOUTC/16)*64*8*2);

  const int nbW4 = (N+3)/4;
  const int nbG  = (N+63)/64;   // 64 rows/block, 4 waves x 16 rows

  pack_kernel<DIN ,DHID ><<<(DIN/32)*(DHID/16)*64/256,  256,0,stream>>>(W1, Wp1);
  pack_kernel<DHID,DHID ><<<(DHID/32)*(DHID/16)*64/256, 256,0,stream>>>(W2, Wp2);
  pack_kernel<DHID,DOUTC><<<(DHID/32)*(DOUTC/16)*64/256,256,0,stream>>>(W3, Wp3);

  // CSR build (atomic-free)
  rs_hist   <<<NB, 256,0,stream>>>(dst, ghist, E, NB);
  rs_scan   <<<256,256,0,stream>>>(ghist, btot, NB);
  rs_scan2  <<<1,  256,0,stream>>>(btot, offsets, N, E);
  rs_scatter<<<NB, 256,0,stream>>>(src, dst, ghist, btot, ebuf, E, NB);
  bucket_sort<<<NHB,256,0,stream>>>(ebuf, btot, offsets, srcs, N);

  // Layer 1: [N,256]@[256,128]
  gemm_v3<DIN,DHID><<<nbG,256,0,stream>>>(h, Wp1, al1, ar1, Fb, el, er, N);
  agg3_kernel<128,true,false><<<nbW4,256,0,stream>>>(Fb, el, er, offsets, srcs, X, N);

  // Layer 2: [N,128]@[128,128]
  gemm_v3<DHID,DHID><<<nbG,256,0,stream>>>(X, Wp2, al2, ar2, Fb, el, er, N);
  agg3_kernel<128,true,false><<<nbW4,256,0,stream>>>(Fb, el, er, offsets, srcs, X, N);

  // Layer 3: [N,128]@[128,64] + log_softmax
  gemm_v3<DHID,DOUTC><<<nbG,256,0,stream>>>(X, Wp3, al3, ar3, Fb, el, er, N);
  agg3_kernel<64,false,true><<<nbW4,256,0,stream>>>(Fb, el, er, offsets, srcs, (float*)d_out, N);
}